// Round 11
// baseline (2225.838 us; speedup 1.0000x reference)
//
#include <hip/hip_runtime.h>
#include <cmath>

#ifndef M_PI
#define M_PI 3.14159265358979323846
#endif

#define T_LEN   160000
#define NSEG    155
#define ROWS    32
#define NBANDS  8

#define CHUNK   256                  // samples per barrier interval
#define NSUB    4                    // sub-chunks of 64
#define NQ      16                   // float4 quads per sub-chunk
#define NCHUNK  624                  // 256*624 = 159744 = all samples any segment uses
#define TOT_IT  (NCHUNK + 2)         // 3-stage pipeline drain
#define LOUD_FLOATS (NBANDS * 2 * ROWS * NSEG)   // 79360

struct AllCoefs {
    float h[NBANDS][5];   // b0 b1 b2 a1 a2 (a0-normalized, f32-cast like np.float32)
    float l[NBANDS][5];
};

// Workgroup barrier without the vmcnt(0) drain (only LDS carries inter-wave
// data; w0's global prefetch stays in flight across the barrier).
__device__ __forceinline__ void barrier_lds_only() {
    asm volatile("s_waitcnt lgkmcnt(0)\n\ts_barrier" ::: "memory");
}

// ============================ Fused pipeline =============================
// One block per (band, src): 32 chains, 3 waves, 256 samples/barrier.
// KEY CHANGE vs R10: each 64-sample block is split into a dependency-free
// FIR phase (all s2's into registers — issue-rate limited) followed by a
// tight REC phase (the 2-FMA/sample feedback chain — the true serial floor).
// R10's measured 28 cyc/sample was the 5-op written chain; the math only
// requires 2 chained FMAs/sample. Grouping FIR ops before REC ops does not
// change any operation or operand -> still BIT-EXACT (absmax 0.0 R3-R10).
//   w0 : hp  (global consume-refill prefetch, distance 2)  -> I1
//   w1 : lp  I1 -> I2
//   w2 : weighting, dual parity (lanes 0-31 even segs, 32-63 odd)
__global__ __launch_bounds__(192, 1)
void tf_pipe3_kernel(const float* __restrict__ sig, const float* __restrict__ wm,
                     float* __restrict__ loud, AllCoefs C) {
    __shared__ float I1[2][CHUNK * 32];   // hp -> lp       (64 KiB)
    __shared__ float I2[2][CHUNK * 32];   // lp -> weight   (64 KiB)

    const int band = blockIdx.x;
    const int src  = blockIdx.y;              // 0 = signal, 1 = watermark
    const int tid  = threadIdx.x;
    const int wid  = tid >> 6;
    const int lane = tid & 63;
    const int ch   = lane & 31;               // chain = batch row

    const float hb0 = C.h[band][0], hb1 = C.h[band][1], hb2 = C.h[band][2];
    const float hna1 = -C.h[band][3], hna2 = -C.h[band][4];
    const float lb0 = C.l[band][0], lb1 = C.l[band][1], lb2 = C.l[band][2];
    const float lna1 = -C.l[band][3], lna2 = -C.l[band][4];
    const float NA1 =  1.79999995231628417969f; // -np.float32(-1.8)
    const float NA2 = -0.810000002384185791f;   // -np.float32(0.81)

    const float* __restrict__ xrow = (src ? wm : sig) + (size_t)ch * T_LEN;
    const float4* __restrict__ xq  = (const float4*)xrow;

    float x1 = 0.f, x2 = 0.f, y1 = 0.f, y2 = 0.f, acc = 0.f;

    float4 pfA[NQ], pfB[NQ];                  // 64-sample ping-pong, distance 2
    if (wid == 0 && lane < 32) {
        #pragma unroll
        for (int i = 0; i < NQ; ++i) pfA[i] = xq[i];        // sub u=0
        #pragma unroll
        for (int i = 0; i < NQ; ++i) pfB[i] = xq[NQ + i];   // sub u=1
    }

// FIR parts (data-only deps; x1,x2 are pure delays -> renamed, no chain):
#define FIRHP(xx, oo) { float s1 = __fmaf_rn(hb0, xx, __fmul_rn(hb1, x1)); \
                        oo = __fmaf_rn(hb2, x2, s1); x2 = x1; x1 = xx; }
#define FIRLP(xx, oo) { float s1 = __fmaf_rn(lb0, xx, __fmul_rn(lb1, x1)); \
                        oo = __fmaf_rn(lb2, x2, s1); x2 = x1; x1 = xx; }
#define FIRW(xx, oo)  { float s1 = __fmaf_rn(-2.0f, x1, xx); \
                        oo = __fadd_rn(s1, x2); x2 = x1; x1 = xx; }
// REC parts (the 2-FMA/sample feedback chains):
#define RECHP(ss, oo) { float s3 = __fmaf_rn(hna1, y1, ss); \
                        oo = __fmaf_rn(hna2, y2, s3); y2 = y1; y1 = oo; }
#define RECLP(ss, oo) { float s3 = __fmaf_rn(lna1, y1, ss); \
                        oo = __fmaf_rn(lna2, y2, s3); y2 = y1; y1 = oo; }
#define RECW(ss)      { float s3 = __fmaf_rn(NA1, y1, ss); \
                        float yy = __fmaf_rn(NA2, y2, s3); \
                        y2 = y1; y1 = yy; acc = __fmaf_rn(yy, yy, acc); }

// w0 sub-chunk: consume BUF (sub u=4c+s), refill from sub u+2 (same parity),
// FIR whole block into fir[], then run the tight hp feedback chain.
// Max refill: u=2495 -> u+2=2497 -> samples 159808..159871 < 160000.
#define W0SUB(BUF, c, s)                                                     \
    {                                                                        \
        float4 fir[NQ];                                                      \
        const float4* __restrict__ nx = xq + (size_t)(4*(c) + (s) + 2) * NQ; \
        _Pragma("unroll")                                                    \
        for (int i = 0; i < NQ; ++i) {                                       \
            float4 v = BUF[i];                                               \
            BUF[i] = nx[i];                                                  \
            FIRHP(v.x, fir[i].x) FIRHP(v.y, fir[i].y)                        \
            FIRHP(v.z, fir[i].z) FIRHP(v.w, fir[i].w)                        \
        }                                                                    \
        float4* __restrict__ ob = (float4*)I1[(c) & 1];                      \
        _Pragma("unroll")                                                    \
        for (int i = 0; i < NQ; ++i) {                                       \
            float4 o;                                                        \
            RECHP(fir[i].x, o.x) RECHP(fir[i].y, o.y)                        \
            RECHP(fir[i].z, o.z) RECHP(fir[i].w, o.w)                        \
            ob[((s) * NQ + i) * 32 + ch] = o;                                \
        }                                                                    \
    }

    for (int iter = 0; iter < TOT_IT; ++iter) {
        if (wid == 0) {
            if (iter < NCHUNK && lane < 32) {
                const int c = iter;
                W0SUB(pfA, c, 0)
                W0SUB(pfB, c, 1)
                W0SUB(pfA, c, 2)
                W0SUB(pfB, c, 3)
            }
        } else if (wid == 1) {
            if (iter >= 1 && iter <= NCHUNK && lane < 32) {
                const int c = iter - 1;
                const float4* __restrict__ ib = (const float4*)I1[c & 1];
                float4* __restrict__ ob = (float4*)I2[c & 1];
                #pragma unroll
                for (int s = 0; s < NSUB; ++s) {
                    float4 v[NQ], fir[NQ];
                    #pragma unroll
                    for (int i = 0; i < NQ; ++i) v[i] = ib[(s * NQ + i) * 32 + ch];
                    #pragma unroll
                    for (int i = 0; i < NQ; ++i) {
                        FIRLP(v[i].x, fir[i].x) FIRLP(v[i].y, fir[i].y)
                        FIRLP(v[i].z, fir[i].z) FIRLP(v[i].w, fir[i].w)
                    }
                    #pragma unroll
                    for (int i = 0; i < NQ; ++i) {
                        float4 o;
                        RECLP(fir[i].x, o.x) RECLP(fir[i].y, o.y)
                        RECLP(fir[i].z, o.z) RECLP(fir[i].w, o.w)
                        ob[(s * NQ + i) * 32 + ch] = o;
                    }
                }
            }
        } else {
            if (iter >= 2) {
                const int c = iter - 2;
                const bool evenHalf = (lane < 32);
                const float4* __restrict__ ib = (const float4*)I2[c & 1];
                #pragma unroll
                for (int s = 0; s < NSUB; ++s) {
                    const int u = c * NSUB + s;       // global 64-sample index
                    const int m32 = u & 31;
                    // segment j = u/16 starts at sub u when u%32==0 (even j) or 16 (odd j)
                    if ((m32 == (evenHalf ? 0 : 16)) && (u >> 4) < NSEG) {
                        x1 = 0.f; x2 = 0.f; y1 = 0.f; y2 = 0.f; acc = 0.f;
                    }
                    float4 v[NQ], fir[NQ];
                    #pragma unroll
                    for (int i = 0; i < NQ; ++i) v[i] = ib[(s * NQ + i) * 32 + ch];
                    #pragma unroll
                    for (int i = 0; i < NQ; ++i) {
                        FIRW(v[i].x, fir[i].x) FIRW(v[i].y, fir[i].y)
                        FIRW(v[i].z, fir[i].z) FIRW(v[i].w, fir[i].w)
                    }
                    #pragma unroll
                    for (int i = 0; i < NQ; ++i) {
                        RECW(fir[i].x) RECW(fir[i].y) RECW(fir[i].z) RECW(fir[i].w)
                    }
                    // even seg ends when u%32==31; odd when u%32==15 (u>=31); j=(u-31)/16
                    const int endm = evenHalf ? 31 : 15;
                    if (m32 == endm && u >= 31) {
                        const int j = (u - 31) >> 4;
                        float e = __fmul_rn(acc, 0.00048828125f);   // /2048 exact
                        loud[((size_t)((band * 2 + src) * ROWS + ch)) * NSEG + j] =
                            __fmul_rn(10.0f, log10f(__fadd_rn(e, 1e-8f)));
                    }
                }
            }
        }
        barrier_lds_only();
    }
#undef W0SUB
#undef FIRHP
#undef FIRLP
#undef FIRW
#undef RECHP
#undef RECLP
#undef RECW
}

__global__ __launch_bounds__(256)
void tf_reduce_kernel(const float* __restrict__ loud, float* __restrict__ out) {
    __shared__ double sh[256];
    const int per_band = ROWS * NSEG;       // 4960
    const int npairs   = NBANDS * per_band; // 39680
    double s = 0.0;
    for (int idx = threadIdx.x; idx < npairs; idx += 256) {
        int band = idx / per_band;
        int rs   = idx - band * per_band;
        float a = loud[(size_t)(band * 2 + 0) * per_band + rs];
        float b = loud[(size_t)(band * 2 + 1) * per_band + rs];
        s += fabs((double)b - (double)a);
    }
    sh[threadIdx.x] = s;
    __syncthreads();
    for (int off = 128; off > 0; off >>= 1) {
        if (threadIdx.x < off) sh[threadIdx.x] += sh[threadIdx.x + off];
        __syncthreads();
    }
    if (threadIdx.x == 0) out[0] = (float)(sh[0] / (double)npairs);
}

// Host-side coefficients: f64 with the reference's exact expression order,
// then cast each to f32 (mirrors tuple(np.float32(v / a0) ...)).
static void mk_hp(double cutoff, float* o) {
    const double w0    = 2.0 * M_PI * cutoff / 16000.0;
    const double alpha = sin(w0) / (2.0 * 0.707);
    const double cw    = cos(w0);
    const double b0 = (1.0 + cw) / 2.0;
    const double b1 = -(1.0 + cw);
    const double b2 = (1.0 + cw) / 2.0;
    const double a0 = 1.0 + alpha;
    const double a1 = -2.0 * cw;
    const double a2 = 1.0 - alpha;
    o[0] = (float)(b0 / a0); o[1] = (float)(b1 / a0); o[2] = (float)(b2 / a0);
    o[3] = (float)(a1 / a0); o[4] = (float)(a2 / a0);
}

static void mk_lp(double cutoff, float* o) {
    const double w0    = 2.0 * M_PI * cutoff / 16000.0;
    const double alpha = sin(w0) / (2.0 * 0.707);
    const double cw    = cos(w0);
    const double b0 = (1.0 - cw) / 2.0;
    const double b1 = 1.0 - cw;
    const double b2 = (1.0 - cw) / 2.0;
    const double a0 = 1.0 + alpha;
    const double a1 = -2.0 * cw;
    const double a2 = 1.0 - alpha;
    o[0] = (float)(b0 / a0); o[1] = (float)(b1 / a0); o[2] = (float)(b2 / a0);
    o[3] = (float)(a1 / a0); o[4] = (float)(a2 / a0);
}

extern "C" void kernel_launch(void* const* d_in, const int* in_sizes, int n_in,
                              void* d_out, int out_size, void* d_ws, size_t ws_size,
                              hipStream_t stream) {
    const float* sig = (const float*)d_in[0];
    const float* wm  = (const float*)d_in[1];
    float* loud = (float*)d_ws;   // 79360 floats = 310 KiB

    AllCoefs C;
    for (int i = 0; i < NBANDS; ++i) {
        mk_hp(1000.0 * (double)i,       C.h[i]);   // low_cut  = i*1000 exactly
        mk_lp(1000.0 * (double)(i + 1), C.l[i]);   // high_cut = (i+1)*1000 exactly
    }

    tf_pipe3_kernel<<<dim3(NBANDS, 2), 192, 0, stream>>>(sig, wm, loud, C);
    tf_reduce_kernel<<<1, 256, 0, stream>>>(loud, (float*)d_out);
}